// Round 11
// baseline (1938.450 us; speedup 1.0000x reference)
//
#include <hip/hip_runtime.h>

// ---------------------------------------------------------------------------
// ReLU-RNN (B=256, T=512, I=64, H=512, O=24), fp32 in/out.  Round 17.
//
// 16 groups (16 batch rows) x 8 members (64 hid cols) = 128 blocks x 256 thr.
//   [round-17] SAFE subset of round-16 on the verified round-14 skeleton:
//              * spec loads + flag pre-load issued in the EPILOGUE (head
//                start ~1500cy) -- but park = FULL wait_vm0 (sound).
//                Round-16's counted vmcnt(4/5) park FAILED (absmax 0.087):
//                vmcnt mixes loads+stores; if the count is off, the tag
//                check reads the PREVIOUS step's P registers, whose tag is
//                VALID for step-pairs {2k,2k+1} (texp=(t>>1)&1) -> stale h
//                accepted.  Counted vmcnt over mixed streams = unverified
//                primitive; full drain is the verified one.
//              * flag fast-accept via pre-loaded Fpre (skip poll when
//                partner already done -> laggard's poll RTT removed).
//              * t=0 forced reload after park (cross-dispatch tag0 race:
//                prev-dispatch h_512 is >=0 -> tag0 == t=0 texp).
//              * MFMA 6 accumulators (2x shorter dep chains).
//              * flag store issued right after data stores (before LDS).
//   [round-14] sc1 scope.  [round-12] absolute flag sequence, no nonce.
//   [round-11] x prefetch one step ahead; epilogue global-stores-first.
//   [round-10] v_cvt_pk_bf16_f32 packing.
// Exchange = tagged fp32 (sign bit = slab-parity tag; h>=0 after relu):
//   * flags (agent-scope) throttle the wait; tags carry correctness
//   * phase-2 bounded per-thread tag-retry fixes stale spans (safety net)
//   * producer: tagged dword stores + flag store with NO vmcnt drain.
// LDS A-planes double-buffered by parity -> 2 barriers/step.
// W_ext=[W_hh|W_ih] (K=576) in VGPRs as bf16 hi/lo frags; bf16x3 MFMA.
// ---------------------------------------------------------------------------

#define T_STEPS 512
#define NG      16
#define NM      8
#define SLAB    32768                    // 16 rows x 512 cols fp32
#define FLAGS_OFF (2 * NG * SLAB)        // 1 MiB
#define POLL_CAP 100000
#define TAG_CAP  20000

// LDS: A planes double-buffered by parity; rows 16 x 1040B (512 bf16 + 8 pad)
#define LA_STRIDE 1040
#define LA_PLANE  16640                  // 16*1040
#define LA_PAR    33280                  // 2*LA_PLANE (hi+lo)
#define LX_OFF    66560                  // 2*LA_PAR
#define LX_STRIDE 144
#define LX_PLANE  2304                   // 16*144; total 71168 B

typedef short          short8  __attribute__((ext_vector_type(8)));
typedef unsigned short bfx4    __attribute__((ext_vector_type(4)));
typedef unsigned       uintx4  __attribute__((ext_vector_type(4)));
typedef float          floatx4 __attribute__((ext_vector_type(4)));
typedef unsigned long long ull;

__device__ __forceinline__ unsigned short f2bf(float x) {
    unsigned u = __float_as_uint(x);
    u = (u + 0x7fffu + ((u >> 16) & 1u)) >> 16;   // RNE
    return (unsigned short)u;
}
__device__ __forceinline__ float bf2f(unsigned short h) {
    return __uint_as_float(((unsigned)h) << 16);
}
// HW packed f32->bf16 (RNE); dst.lo16=cvt(a), dst.hi16=cvt(b)
__device__ __forceinline__ unsigned cvtpk(float a, float b) {
    unsigned r;
    asm("v_cvt_pk_bf16_f32 %0, %1, %2" : "=v"(r) : "v"(a), "v"(b));
    return r;
}
// 4 fp32 -> packed bf16 hi plane (4x16b) + lo plane (residual, 4x16b)
__device__ __forceinline__ void pack_hilo(float f0, float f1, float f2, float f3,
                                          ull& hi, ull& lo) {
    const unsigned h01 = cvtpk(f0, f1), h23 = cvtpk(f2, f3);
    const float l0 = f0 - __uint_as_float(h01 << 16);
    const float l1 = f1 - __uint_as_float(h01 & 0xffff0000u);
    const float l2 = f2 - __uint_as_float(h23 << 16);
    const float l3 = f3 - __uint_as_float(h23 & 0xffff0000u);
    const unsigned q01 = cvtpk(l0, l1), q23 = cvtpk(l2, l3);
    hi = (ull)h01 | ((ull)h23 << 32);
    lo = (ull)q01 | ((ull)q23 << 32);
}
__device__ __forceinline__ void st_ag_u32(void* p, unsigned v) {
    __hip_atomic_store((unsigned*)p, v, __ATOMIC_RELAXED, __HIP_MEMORY_SCOPE_AGENT);
}
__device__ __forceinline__ unsigned ld_ag_u32(const void* p) {
    return __hip_atomic_load((const unsigned*)p, __ATOMIC_RELAXED, __HIP_MEMORY_SCOPE_AGENT);
}
// AGENT-scope (sc1) data ops
__device__ __forceinline__ uintx4 ld_ag_b128_async(const void* p) {
    uintx4 v;
    asm volatile("global_load_dwordx4 %0, %1, off sc1"
                 : "=v"(v) : "v"(p) : "memory");
    return v;
}
__device__ __forceinline__ unsigned ld_flag_async(const unsigned* p) {
    unsigned v;
    asm volatile("global_load_dword %0, %1, off sc1"
                 : "=v"(v) : "v"(p) : "memory");
    return v;
}
__device__ __forceinline__ void st_ag_b32(void* p, unsigned v) {
    asm volatile("global_store_dword %0, %1, off sc1"
                 :: "v"(p), "v"(v) : "memory");
}
__device__ __forceinline__ void st_ag_b128(void* p, uintx4 v) {
    asm volatile("global_store_dwordx4 %0, %1, off sc1"
                 :: "v"(p), "v"(v) : "memory");
}
__device__ __forceinline__ void wait_vm0() {
    asm volatile("s_waitcnt vmcnt(0)" ::: "memory");
}
__device__ __forceinline__ void poll_flag(const unsigned* p, unsigned want) {
    int it = 0;
    for (;;) {
        unsigned f = ld_ag_u32(p);
        if (f == want || f == want + 1u) return;
        if (++it >= POLL_CAP) return;            // tags still protect data
    }
}

#define MFMA_BF16 __builtin_amdgcn_mfma_f32_16x16x32_bf16

__global__ __launch_bounds__(256, 1) void rnn_persistent(
    const float* __restrict__ x,     const float* __restrict__ W_ih,
    const float* __restrict__ W_hh,  const float* __restrict__ b_ih,
    const float* __restrict__ b_hh,  const float* __restrict__ fc_w,
    const float* __restrict__ fc_b,  float* __restrict__ out,
    unsigned char* __restrict__ ws)
{
    const int tid  = threadIdx.x;
    const int lane = tid & 63;
    const int w    = tid >> 6;        // wave 0..3
    const int n    = lane & 15;
    const int quad = lane >> 4;

    const int bid = blockIdx.x;
    const int g = bid >> 3;           // group 0..15
    const int m = bid & 7;            // member 0..7

    unsigned char* ex = (unsigned char*)ws;
    unsigned* flagbase = (unsigned*)(ex + FLAGS_OFF + g * 64);
    __shared__ __align__(16) unsigned char smem[LX_OFF + 2 * LX_PLANE];

    // ---- W fragments: wave w holds cols (=W rows) m*64+w*16 .. +16 ----
    const int wrow = m * 64 + w * 16 + n;
    short8 Whi[18], Wlo[18];
    #pragma unroll
    for (int kt = 0; kt < 18; ++kt) {
        const float* p = (kt < 16) ? (W_hh + wrow * 512 + kt * 32 + quad * 8)
                                   : (W_ih + wrow * 64 + (kt - 16) * 32 + quad * 8);
        #pragma unroll
        for (int jj = 0; jj < 8; ++jj) {
            float f = p[jj];
            unsigned short h = f2bf(f);
            Whi[kt][jj] = (short)h;
            Wlo[kt][jj] = (short)f2bf(f - bf2f(h));
        }
    }
    const float bias_i = b_ih[wrow] + b_hh[wrow];

    // ---- per-thread partner span mapping (row prow, 16B at pc4) ----
    const int prow = tid >> 4, pc4 = tid & 15;
    int poff[7];
    #pragma unroll
    for (int r = 0; r < 7; ++r) {
        const int pm = r + (r >= m ? 1 : 0);
        poff[r] = prow * 2048 + pm * 256 + pc4 * 16;
    }

    // ---- init: own chunk = +0.0 (tag0) in parity-0 slab; own LDS cols = 0
    {
        uintx4 z = {0u, 0u, 0u, 0u};
        st_ag_b128(ex + g * SLAB + prow * 2048 + m * 256 + pc4 * 16, z);
        #pragma unroll
        for (int r = 0; r < 4; ++r) {
            const int row = quad * 4 + r;
            *(unsigned short*)(smem + 0 * LA_PLANE + row * LA_STRIDE + wrow * 2) = 0;
            *(unsigned short*)(smem + LA_PLANE + row * LA_STRIDE + wrow * 2) = 0;
        }
    }
    wait_vm0();
    __syncthreads();
    // init flag = 1 ("h_0 ready"); zeros drained before this store.
    if (tid == 0) st_ag_u32(flagbase + m, 1u);

    // ---- recurrence ------------------------------------------------------
    const int xrow = tid >> 4, xi4 = tid & 15;
    const float* xbase = x + (size_t)(g * 16 + xrow) * T_STEPS * 64 + xi4 * 4;
    float4 xv_cur = *(const float4*)(xbase + 0 * 64);

    uintx4 P[7];
    unsigned Fpre = 0u;

    for (int t = 0; t < T_STEPS; ++t) {
        const unsigned texp = (((unsigned)t >> 1) & 1u) << 31;
        const unsigned char* slab_r = ex + ((t & 1) * NG + g) * SLAB;
        const unsigned want = (unsigned)t + 1u;

        // ---- park: FULL drain (sound) ------------------------------------
        wait_vm0();
        __builtin_amdgcn_sched_barrier(0);
        // flag fast-accept via pre-loaded value; else park (slow path)
        if (tid < 7) {
            const bool ok = (t > 0) && (Fpre == want || Fpre == want + 1u);
            if (!ok) {
                const int pm = tid + (tid >= m ? 1 : 0);
                poll_flag(flagbase + pm, want);
            }
        }
        __syncthreads();                                   // (a)

        // t=0: forced reload (closes cross-dispatch tag0 collision race;
        // flag=1 implies partner zeros drained -> reload is guaranteed fresh)
        if (t == 0) {
            #pragma unroll
            for (int r = 0; r < 7; ++r) P[r] = ld_ag_b128_async(slab_r + poff[r]);
            wait_vm0();
            __builtin_amdgcn_sched_barrier(0);
        }

        // phase-2: bounded per-thread tag-retry for stale spans
        {
            int it = 0;
            for (;;) {
                unsigned bad = 0;
                #pragma unroll
                for (int r = 0; r < 7; ++r)
                    bad |= (P[r].x ^ texp) | (P[r].y ^ texp)
                         | (P[r].z ^ texp) | (P[r].w ^ texp);
                if (!(bad & 0x80000000u) || ++it >= TAG_CAP) break;
                #pragma unroll
                for (int r = 0; r < 7; ++r) P[r] = ld_ag_b128_async(slab_r + poff[r]);
                wait_vm0();
            }
        }

        // x prefetch for t+1 (HBM; a full step to complete)
        const int tn = (t + 1 < T_STEPS) ? (t + 1) : (T_STEPS - 1);
        const float4 xv_nxt = *(const float4*)(xbase + (size_t)tn * 64);

        // convert partner cols -> LDS A planes (parity t&1)
        unsigned char* abase = smem + (t & 1) * LA_PAR;
        #pragma unroll
        for (int r = 0; r < 7; ++r) {
            const int pm = r + (r >= m ? 1 : 0);
            ull hi, lo;
            pack_hilo(__uint_as_float(P[r].x & 0x7fffffffu),
                      __uint_as_float(P[r].y & 0x7fffffffu),
                      __uint_as_float(P[r].z & 0x7fffffffu),
                      __uint_as_float(P[r].w & 0x7fffffffu), hi, lo);
            const int base = prow * LA_STRIDE + pm * 128 + pc4 * 8;
            *(ull*)(abase + base)            = hi;
            *(ull*)(abase + LA_PLANE + base) = lo;
        }
        // stage x_t (fp32 -> bf16 hi/lo) from prefetched regs
        {
            ull hi, lo;
            pack_hilo(xv_cur.x, xv_cur.y, xv_cur.z, xv_cur.w, hi, lo);
            *(ull*)(smem + LX_OFF + xrow * LX_STRIDE + xi4 * 8)            = hi;
            *(ull*)(smem + LX_OFF + LX_PLANE + xrow * LX_STRIDE + xi4 * 8) = lo;
        }
        __syncthreads();                                   // (b)

        // MFMA: C[16 batch x 16 cols] over K=576, bf16x3, 6 short acc chains
        floatx4 c0a = {0.f,0.f,0.f,0.f}, c1a = {0.f,0.f,0.f,0.f}, c2a = {0.f,0.f,0.f,0.f};
        floatx4 c0b = {0.f,0.f,0.f,0.f}, c1b = {0.f,0.f,0.f,0.f}, c2b = {0.f,0.f,0.f,0.f};
        #pragma unroll
        for (int kt = 0; kt < 8; ++kt) {
            const unsigned char* ba = abase + n * LA_STRIDE + kt * 64 + quad * 16;
            short8 ah = *(const short8*)(ba);
            short8 al = *(const short8*)(ba + LA_PLANE);
            c0a = MFMA_BF16(ah, Whi[kt], c0a, 0, 0, 0);
            c1a = MFMA_BF16(al, Whi[kt], c1a, 0, 0, 0);
            c2a = MFMA_BF16(ah, Wlo[kt], c2a, 0, 0, 0);
        }
        #pragma unroll
        for (int kt = 8; kt < 16; ++kt) {
            const unsigned char* ba = abase + n * LA_STRIDE + kt * 64 + quad * 16;
            short8 ah = *(const short8*)(ba);
            short8 al = *(const short8*)(ba + LA_PLANE);
            c0b = MFMA_BF16(ah, Whi[kt], c0b, 0, 0, 0);
            c1b = MFMA_BF16(al, Whi[kt], c1b, 0, 0, 0);
            c2b = MFMA_BF16(ah, Wlo[kt], c2b, 0, 0, 0);
        }
        #pragma unroll
        for (int kt = 16; kt < 18; ++kt) {
            const unsigned char* ba = smem + LX_OFF + n * LX_STRIDE + (kt - 16) * 64 + quad * 16;
            short8 ah = *(const short8*)(ba);
            short8 al = *(const short8*)(ba + LX_PLANE);
            c0a = MFMA_BF16(ah, Whi[kt], c0a, 0, 0, 0);
            c1a = MFMA_BF16(al, Whi[kt], c1a, 0, 0, 0);
            c2a = MFMA_BF16(ah, Wlo[kt], c2a, 0, 0, 0);
        }
        const floatx4 cs = (c0a + c0b) + ((c1a + c1b) + (c2a + c2b));

        // epilogue: v -> pre-issue t+1 spec/flag loads -> tagged stores ->
        // flag store -> LDS own-col writes.  Park next step = full drain.
        const unsigned otag = ((((unsigned)t + 1u) >> 1) & 1u) << 31;
        unsigned char* slab_w = ex + (((t + 1) & 1) * NG + g) * SLAB;
        unsigned char* obase  = smem + ((t + 1) & 1) * LA_PAR;
        const int r0 = quad * 4;
        {
            const float v0 = fmaxf(cs[0] + bias_i, 0.f);
            const float v1 = fmaxf(cs[1] + bias_i, 0.f);
            const float v2 = fmaxf(cs[2] + bias_i, 0.f);
            const float v3 = fmaxf(cs[3] + bias_i, 0.f);

            // pre-issue next step's spec loads + flag pre-load (head start;
            // the next park's wait_vm0 covers them)
            if (t + 1 < T_STEPS) {
                #pragma unroll
                for (int r = 0; r < 7; ++r)
                    P[r] = ld_ag_b128_async(slab_w + poff[r]);
                if (tid < 7) {
                    const int pm7 = tid + (tid >= m ? 1 : 0);
                    Fpre = ld_flag_async(flagbase + pm7);
                }
            }

            st_ag_b32(slab_w + (r0+0) * 2048 + wrow * 4, __float_as_uint(v0) | otag);
            st_ag_b32(slab_w + (r0+1) * 2048 + wrow * 4, __float_as_uint(v1) | otag);
            st_ag_b32(slab_w + (r0+2) * 2048 + wrow * 4, __float_as_uint(v2) | otag);
            st_ag_b32(slab_w + (r0+3) * 2048 + wrow * 4, __float_as_uint(v3) | otag);
            if (tid == 0) st_ag_u32(flagbase + m, (unsigned)t + 2u);

            const unsigned h01 = cvtpk(v0, v1), h23 = cvtpk(v2, v3);
            const float l0 = v0 - __uint_as_float(h01 << 16);
            const float l1 = v1 - __uint_as_float(h01 & 0xffff0000u);
            const float l2 = v2 - __uint_as_float(h23 << 16);
            const float l3 = v3 - __uint_as_float(h23 & 0xffff0000u);
            const unsigned q01 = cvtpk(l0, l1), q23 = cvtpk(l2, l3);
            *(unsigned short*)(obase + (r0+0) * LA_STRIDE + wrow * 2) = (unsigned short)(h01 & 0xffffu);
            *(unsigned short*)(obase + (r0+1) * LA_STRIDE + wrow * 2) = (unsigned short)(h01 >> 16);
            *(unsigned short*)(obase + (r0+2) * LA_STRIDE + wrow * 2) = (unsigned short)(h23 & 0xffffu);
            *(unsigned short*)(obase + (r0+3) * LA_STRIDE + wrow * 2) = (unsigned short)(h23 >> 16);
            *(unsigned short*)(obase + LA_PLANE + (r0+0) * LA_STRIDE + wrow * 2) = (unsigned short)(q01 & 0xffffu);
            *(unsigned short*)(obase + LA_PLANE + (r0+1) * LA_STRIDE + wrow * 2) = (unsigned short)(q01 >> 16);
            *(unsigned short*)(obase + LA_PLANE + (r0+2) * LA_STRIDE + wrow * 2) = (unsigned short)(q23 & 0xffffu);
            *(unsigned short*)(obase + LA_PLANE + (r0+3) * LA_STRIDE + wrow * 2) = (unsigned short)(q23 >> 16);
        }
        xv_cur = xv_nxt;
    }

    // ---- fc on h_512 (member 0 only; own cols already in LDS parity 0) ---
    if (m != 0) return;
    {
        const unsigned texp = 0;                           // tag of h_512
        const unsigned char* slab_r = ex + (0 * NG + g) * SLAB;
        uintx4 Pf[7];
        #pragma unroll
        for (int r = 0; r < 7; ++r) Pf[r] = ld_ag_b128_async(slab_r + poff[r]);
        if (tid < 7) poll_flag(flagbase + (tid + 1), (unsigned)T_STEPS + 1u);
        wait_vm0();
        __syncthreads();
        int it = 0;
        for (;;) {
            unsigned bad = 0;
            #pragma unroll
            for (int r = 0; r < 7; ++r)
                bad |= (Pf[r].x ^ texp) | (Pf[r].y ^ texp)
                     | (Pf[r].z ^ texp) | (Pf[r].w ^ texp);
            if (!(bad & 0x80000000u) || ++it >= TAG_CAP) break;
            #pragma unroll
            for (int r = 0; r < 7; ++r) Pf[r] = ld_ag_b128_async(slab_r + poff[r]);
            wait_vm0();
        }
        unsigned char* abase = smem;                       // parity 0
        #pragma unroll
        for (int r = 0; r < 7; ++r) {
            const int pm = r + 1;
            ull hi, lo;
            pack_hilo(__uint_as_float(Pf[r].x & 0x7fffffffu),
                      __uint_as_float(Pf[r].y & 0x7fffffffu),
                      __uint_as_float(Pf[r].z & 0x7fffffffu),
                      __uint_as_float(Pf[r].w & 0x7fffffffu), hi, lo);
            const int base = prow * LA_STRIDE + pm * 128 + pc4 * 8;
            *(ull*)(abase + base)            = hi;
            *(ull*)(abase + LA_PLANE + base) = lo;
        }
    }
    __syncthreads();
    for (int idx = tid; idx < 384; idx += 256) {
        const int row = idx / 24, o = idx % 24;
        const float* wp = fc_w + o * 512;
        float s = 0.f;
        for (int k = 0; k < 512; k += 4) {
            bfx4 hv = *(const bfx4*)(smem + row * LA_STRIDE + k * 2);
            bfx4 lv = *(const bfx4*)(smem + LA_PLANE + row * LA_STRIDE + k * 2);
            const float4 wv = *(const float4*)(wp + k);
            s += (bf2f(hv[0]) + bf2f(lv[0])) * wv.x;
            s += (bf2f(hv[1]) + bf2f(lv[1])) * wv.y;
            s += (bf2f(hv[2]) + bf2f(lv[2])) * wv.z;
            s += (bf2f(hv[3]) + bf2f(lv[3])) * wv.w;
        }
        out[(g * 16 + row) * 24 + o] = s + fc_b[o];
    }
}

extern "C" void kernel_launch(void* const* d_in, const int* in_sizes, int n_in,
                              void* d_out, int out_size, void* d_ws, size_t ws_size,
                              hipStream_t stream) {
    (void)in_sizes; (void)n_in; (void)out_size; (void)ws_size;
    const float* x    = (const float*)d_in[0];
    const float* W_ih = (const float*)d_in[1];
    const float* W_hh = (const float*)d_in[2];
    const float* b_ih = (const float*)d_in[3];
    const float* b_hh = (const float*)d_in[4];
    const float* fc_w = (const float*)d_in[5];
    const float* fc_b = (const float*)d_in[6];
    rnn_persistent<<<NG * NM, 256, 0, stream>>>(x, W_ih, W_hh, b_ih, b_hh,
                                                fc_w, fc_b, (float*)d_out,
                                                (unsigned char*)d_ws);
}

// Round 12
// 1530.243 us; speedup vs baseline: 1.2668x; 1.2668x over previous
//
#include <hip/hip_runtime.h>

// ---------------------------------------------------------------------------
// ReLU-RNN (B=256, T=512, I=64, H=512, O=24), fp32 in/out.  Round 18.
//
// 16 groups (16 batch rows) x 8 members (64 hid cols) = 128 blocks x 256 thr.
//   [round-18] REVERT to round-14 spec-load placement (step top).  Round-17
//              lesson: loads issued in the EPILOGUE are serviced ~700cy
//              later = BEFORE partners store h_{t+1} -> stale -> tag-retry
//              every step (+11MB FETCH, +490us).  Speculation must be
//              serviced DURING the park, not before the producer's window.
//              Kept from round-17: t=0 forced reload (cross-dispatch tag0
//              race insurance), 6-acc MFMA, flag store right after data
//              stores (producer readiness ~180cy earlier).
//   [round-14] sc1 scope.  [round-12] absolute flag sequence, no nonce.
//   [round-11] x prefetch one step ahead; epilogue global-stores-first.
//   [round-10] v_cvt_pk_bf16_f32 packing.
// Exchange = tagged fp32 (sign bit = slab-parity tag; h>=0 after relu):
//   * flags (agent-scope, 7 polling threads) throttle the wait
//   * sign-bit tags carry data-freshness correctness
//   * phase-1 SPECULATIVE partner loads issued before the poll
//   * phase-2 bounded per-thread tag-retry fixes stale spans
//   * producer: tagged dword stores + flag store with NO vmcnt drain.
// LDS A-planes double-buffered by parity -> 2 barriers/step.
// W_ext=[W_hh|W_ih] (K=576) in VGPRs as bf16 hi/lo frags; bf16x3 MFMA.
// ---------------------------------------------------------------------------

#define T_STEPS 512
#define NG      16
#define NM      8
#define SLAB    32768                    // 16 rows x 512 cols fp32
#define FLAGS_OFF (2 * NG * SLAB)        // 1 MiB
#define POLL_CAP 100000
#define TAG_CAP  20000

// LDS: A planes double-buffered by parity; rows 16 x 1040B (512 bf16 + 8 pad)
#define LA_STRIDE 1040
#define LA_PLANE  16640                  // 16*1040
#define LA_PAR    33280                  // 2*LA_PLANE (hi+lo)
#define LX_OFF    66560                  // 2*LA_PAR
#define LX_STRIDE 144
#define LX_PLANE  2304                   // 16*144; total 71168 B

typedef short          short8  __attribute__((ext_vector_type(8)));
typedef unsigned short bfx4    __attribute__((ext_vector_type(4)));
typedef unsigned       uintx4  __attribute__((ext_vector_type(4)));
typedef float          floatx4 __attribute__((ext_vector_type(4)));
typedef unsigned long long ull;

__device__ __forceinline__ unsigned short f2bf(float x) {
    unsigned u = __float_as_uint(x);
    u = (u + 0x7fffu + ((u >> 16) & 1u)) >> 16;   // RNE
    return (unsigned short)u;
}
__device__ __forceinline__ float bf2f(unsigned short h) {
    return __uint_as_float(((unsigned)h) << 16);
}
// HW packed f32->bf16 (RNE); dst.lo16=cvt(a), dst.hi16=cvt(b)
__device__ __forceinline__ unsigned cvtpk(float a, float b) {
    unsigned r;
    asm("v_cvt_pk_bf16_f32 %0, %1, %2" : "=v"(r) : "v"(a), "v"(b));
    return r;
}
// 4 fp32 -> packed bf16 hi plane (4x16b) + lo plane (residual, 4x16b)
__device__ __forceinline__ void pack_hilo(float f0, float f1, float f2, float f3,
                                          ull& hi, ull& lo) {
    const unsigned h01 = cvtpk(f0, f1), h23 = cvtpk(f2, f3);
    const float l0 = f0 - __uint_as_float(h01 << 16);
    const float l1 = f1 - __uint_as_float(h01 & 0xffff0000u);
    const float l2 = f2 - __uint_as_float(h23 << 16);
    const float l3 = f3 - __uint_as_float(h23 & 0xffff0000u);
    const unsigned q01 = cvtpk(l0, l1), q23 = cvtpk(l2, l3);
    hi = (ull)h01 | ((ull)h23 << 32);
    lo = (ull)q01 | ((ull)q23 << 32);
}
__device__ __forceinline__ void st_ag_u32(void* p, unsigned v) {
    __hip_atomic_store((unsigned*)p, v, __ATOMIC_RELAXED, __HIP_MEMORY_SCOPE_AGENT);
}
__device__ __forceinline__ unsigned ld_ag_u32(const void* p) {
    return __hip_atomic_load((const unsigned*)p, __ATOMIC_RELAXED, __HIP_MEMORY_SCOPE_AGENT);
}
// AGENT-scope (sc1) data ops
__device__ __forceinline__ uintx4 ld_ag_b128_async(const void* p) {
    uintx4 v;
    asm volatile("global_load_dwordx4 %0, %1, off sc1"
                 : "=v"(v) : "v"(p) : "memory");
    return v;
}
__device__ __forceinline__ void st_ag_b32(void* p, unsigned v) {
    asm volatile("global_store_dword %0, %1, off sc1"
                 :: "v"(p), "v"(v) : "memory");
}
__device__ __forceinline__ void st_ag_b128(void* p, uintx4 v) {
    asm volatile("global_store_dwordx4 %0, %1, off sc1"
                 :: "v"(p), "v"(v) : "memory");
}
__device__ __forceinline__ void wait_vm0() {
    asm volatile("s_waitcnt vmcnt(0)" ::: "memory");
}
__device__ __forceinline__ void poll_flag(const unsigned* p, unsigned want) {
    int it = 0;
    for (;;) {
        unsigned f = ld_ag_u32(p);
        if (f == want || f == want + 1u) return;
        if (++it >= POLL_CAP) return;            // tags still protect data
    }
}

#define MFMA_BF16 __builtin_amdgcn_mfma_f32_16x16x32_bf16

__global__ __launch_bounds__(256, 1) void rnn_persistent(
    const float* __restrict__ x,     const float* __restrict__ W_ih,
    const float* __restrict__ W_hh,  const float* __restrict__ b_ih,
    const float* __restrict__ b_hh,  const float* __restrict__ fc_w,
    const float* __restrict__ fc_b,  float* __restrict__ out,
    unsigned char* __restrict__ ws)
{
    const int tid  = threadIdx.x;
    const int lane = tid & 63;
    const int w    = tid >> 6;        // wave 0..3
    const int n    = lane & 15;
    const int quad = lane >> 4;

    const int bid = blockIdx.x;
    const int g = bid >> 3;           // group 0..15
    const int m = bid & 7;            // member 0..7

    unsigned char* ex = (unsigned char*)ws;
    unsigned* flagbase = (unsigned*)(ex + FLAGS_OFF + g * 64);
    __shared__ __align__(16) unsigned char smem[LX_OFF + 2 * LX_PLANE];

    // ---- W fragments: wave w holds cols (=W rows) m*64+w*16 .. +16 ----
    const int wrow = m * 64 + w * 16 + n;
    short8 Whi[18], Wlo[18];
    #pragma unroll
    for (int kt = 0; kt < 18; ++kt) {
        const float* p = (kt < 16) ? (W_hh + wrow * 512 + kt * 32 + quad * 8)
                                   : (W_ih + wrow * 64 + (kt - 16) * 32 + quad * 8);
        #pragma unroll
        for (int jj = 0; jj < 8; ++jj) {
            float f = p[jj];
            unsigned short h = f2bf(f);
            Whi[kt][jj] = (short)h;
            Wlo[kt][jj] = (short)f2bf(f - bf2f(h));
        }
    }
    const float bias_i = b_ih[wrow] + b_hh[wrow];

    // ---- per-thread partner span mapping (row prow, 16B at pc4) ----
    const int prow = tid >> 4, pc4 = tid & 15;
    int poff[7];
    #pragma unroll
    for (int r = 0; r < 7; ++r) {
        const int pm = r + (r >= m ? 1 : 0);
        poff[r] = prow * 2048 + pm * 256 + pc4 * 16;
    }

    // ---- init: own chunk = +0.0 (tag0) in parity-0 slab; own LDS cols = 0
    {
        uintx4 z = {0u, 0u, 0u, 0u};
        st_ag_b128(ex + g * SLAB + prow * 2048 + m * 256 + pc4 * 16, z);
        #pragma unroll
        for (int r = 0; r < 4; ++r) {
            const int row = quad * 4 + r;
            *(unsigned short*)(smem + 0 * LA_PLANE + row * LA_STRIDE + wrow * 2) = 0;
            *(unsigned short*)(smem + LA_PLANE + row * LA_STRIDE + wrow * 2) = 0;
        }
    }
    wait_vm0();
    __syncthreads();
    // init flag = 1 ("h_0 ready"); zeros drained before this store.
    if (tid == 0) st_ag_u32(flagbase + m, 1u);

    // ---- recurrence ------------------------------------------------------
    const int xrow = tid >> 4, xi4 = tid & 15;
    const float* xbase = x + (size_t)(g * 16 + xrow) * T_STEPS * 64 + xi4 * 4;
    float4 xv_cur = *(const float4*)(xbase + 0 * 64);

    for (int t = 0; t < T_STEPS; ++t) {
        const unsigned texp = (((unsigned)t >> 1) & 1u) << 31;
        const unsigned char* slab_r = ex + ((t & 1) * NG + g) * SLAB;
        const unsigned want = (unsigned)t + 1u;

        // phase-1: speculative partner loads (issued at step top ->
        // serviced DURING the flag park; round-17 lesson: not earlier)
        uintx4 P[7];
        #pragma unroll
        for (int r = 0; r < 7; ++r) P[r] = ld_ag_b128_async(slab_r + poff[r]);

        // flag park (7 threads only - no data-poll storm); want = t+1
        if (tid < 7) {
            const int pm = tid + (tid >= m ? 1 : 0);
            poll_flag(flagbase + pm, want);
        }
        wait_vm0();
        __syncthreads();                                   // (a)

        // t=0: forced reload (closes cross-dispatch tag0 collision race;
        // flag=1 implies partner zeros drained -> reload is guaranteed fresh)
        if (t == 0) {
            #pragma unroll
            for (int r = 0; r < 7; ++r) P[r] = ld_ag_b128_async(slab_r + poff[r]);
            wait_vm0();
            __builtin_amdgcn_sched_barrier(0);
        }

        // phase-2: bounded per-thread tag-retry for stale spans
        {
            int it = 0;
            for (;;) {
                unsigned bad = 0;
                #pragma unroll
                for (int r = 0; r < 7; ++r)
                    bad |= (P[r].x ^ texp) | (P[r].y ^ texp)
                         | (P[r].z ^ texp) | (P[r].w ^ texp);
                if (!(bad & 0x80000000u) || ++it >= TAG_CAP) break;
                #pragma unroll
                for (int r = 0; r < 7; ++r) P[r] = ld_ag_b128_async(slab_r + poff[r]);
                wait_vm0();
            }
        }

        // x prefetch for t+1 (HBM; issued AFTER retry so no drain waits on it)
        const int tn = (t + 1 < T_STEPS) ? (t + 1) : (T_STEPS - 1);
        const float4 xv_nxt = *(const float4*)(xbase + (size_t)tn * 64);

        // convert partner cols -> LDS A planes (parity t&1)
        unsigned char* abase = smem + (t & 1) * LA_PAR;
        #pragma unroll
        for (int r = 0; r < 7; ++r) {
            const int pm = r + (r >= m ? 1 : 0);
            ull hi, lo;
            pack_hilo(__uint_as_float(P[r].x & 0x7fffffffu),
                      __uint_as_float(P[r].y & 0x7fffffffu),
                      __uint_as_float(P[r].z & 0x7fffffffu),
                      __uint_as_float(P[r].w & 0x7fffffffu), hi, lo);
            const int base = prow * LA_STRIDE + pm * 128 + pc4 * 8;
            *(ull*)(abase + base)            = hi;
            *(ull*)(abase + LA_PLANE + base) = lo;
        }
        // stage x_t (fp32 -> bf16 hi/lo) from prefetched regs
        {
            ull hi, lo;
            pack_hilo(xv_cur.x, xv_cur.y, xv_cur.z, xv_cur.w, hi, lo);
            *(ull*)(smem + LX_OFF + xrow * LX_STRIDE + xi4 * 8)            = hi;
            *(ull*)(smem + LX_OFF + LX_PLANE + xrow * LX_STRIDE + xi4 * 8) = lo;
        }
        __syncthreads();                                   // (b)

        // MFMA: C[16 batch x 16 cols] over K=576, bf16x3, 6 short acc chains
        floatx4 c0a = {0.f,0.f,0.f,0.f}, c1a = {0.f,0.f,0.f,0.f}, c2a = {0.f,0.f,0.f,0.f};
        floatx4 c0b = {0.f,0.f,0.f,0.f}, c1b = {0.f,0.f,0.f,0.f}, c2b = {0.f,0.f,0.f,0.f};
        #pragma unroll
        for (int kt = 0; kt < 8; ++kt) {
            const unsigned char* ba = abase + n * LA_STRIDE + kt * 64 + quad * 16;
            short8 ah = *(const short8*)(ba);
            short8 al = *(const short8*)(ba + LA_PLANE);
            c0a = MFMA_BF16(ah, Whi[kt], c0a, 0, 0, 0);
            c1a = MFMA_BF16(al, Whi[kt], c1a, 0, 0, 0);
            c2a = MFMA_BF16(ah, Wlo[kt], c2a, 0, 0, 0);
        }
        #pragma unroll
        for (int kt = 8; kt < 16; ++kt) {
            const unsigned char* ba = abase + n * LA_STRIDE + kt * 64 + quad * 16;
            short8 ah = *(const short8*)(ba);
            short8 al = *(const short8*)(ba + LA_PLANE);
            c0b = MFMA_BF16(ah, Whi[kt], c0b, 0, 0, 0);
            c1b = MFMA_BF16(al, Whi[kt], c1b, 0, 0, 0);
            c2b = MFMA_BF16(ah, Wlo[kt], c2b, 0, 0, 0);
        }
        #pragma unroll
        for (int kt = 16; kt < 18; ++kt) {
            const unsigned char* ba = smem + LX_OFF + n * LX_STRIDE + (kt - 16) * 64 + quad * 16;
            short8 ah = *(const short8*)(ba);
            short8 al = *(const short8*)(ba + LX_PLANE);
            c0a = MFMA_BF16(ah, Whi[kt], c0a, 0, 0, 0);
            c1a = MFMA_BF16(al, Whi[kt], c1a, 0, 0, 0);
            c2a = MFMA_BF16(ah, Wlo[kt], c2a, 0, 0, 0);
        }
        const floatx4 cs = (c0a + c0b) + ((c1a + c1b) + (c2a + c2b));

        // epilogue: tagged GLOBAL stores -> flag store -> LDS own-col writes.
        // NO drain: tags carry freshness; flag is only a throttle.
        const unsigned otag = ((((unsigned)t + 1u) >> 1) & 1u) << 31;
        unsigned char* slab_w = ex + (((t + 1) & 1) * NG + g) * SLAB;
        unsigned char* obase  = smem + ((t + 1) & 1) * LA_PAR;
        const int r0 = quad * 4;
        {
            const float v0 = fmaxf(cs[0] + bias_i, 0.f);
            const float v1 = fmaxf(cs[1] + bias_i, 0.f);
            const float v2 = fmaxf(cs[2] + bias_i, 0.f);
            const float v3 = fmaxf(cs[3] + bias_i, 0.f);
            st_ag_b32(slab_w + (r0+0) * 2048 + wrow * 4, __float_as_uint(v0) | otag);
            st_ag_b32(slab_w + (r0+1) * 2048 + wrow * 4, __float_as_uint(v1) | otag);
            st_ag_b32(slab_w + (r0+2) * 2048 + wrow * 4, __float_as_uint(v2) | otag);
            st_ag_b32(slab_w + (r0+3) * 2048 + wrow * 4, __float_as_uint(v3) | otag);
            if (tid == 0) st_ag_u32(flagbase + m, (unsigned)t + 2u);

            const unsigned h01 = cvtpk(v0, v1), h23 = cvtpk(v2, v3);
            const float l0 = v0 - __uint_as_float(h01 << 16);
            const float l1 = v1 - __uint_as_float(h01 & 0xffff0000u);
            const float l2 = v2 - __uint_as_float(h23 << 16);
            const float l3 = v3 - __uint_as_float(h23 & 0xffff0000u);
            const unsigned q01 = cvtpk(l0, l1), q23 = cvtpk(l2, l3);
            *(unsigned short*)(obase + (r0+0) * LA_STRIDE + wrow * 2) = (unsigned short)(h01 & 0xffffu);
            *(unsigned short*)(obase + (r0+1) * LA_STRIDE + wrow * 2) = (unsigned short)(h01 >> 16);
            *(unsigned short*)(obase + (r0+2) * LA_STRIDE + wrow * 2) = (unsigned short)(h23 & 0xffffu);
            *(unsigned short*)(obase + (r0+3) * LA_STRIDE + wrow * 2) = (unsigned short)(h23 >> 16);
            *(unsigned short*)(obase + LA_PLANE + (r0+0) * LA_STRIDE + wrow * 2) = (unsigned short)(q01 & 0xffffu);
            *(unsigned short*)(obase + LA_PLANE + (r0+1) * LA_STRIDE + wrow * 2) = (unsigned short)(q01 >> 16);
            *(unsigned short*)(obase + LA_PLANE + (r0+2) * LA_STRIDE + wrow * 2) = (unsigned short)(q23 & 0xffffu);
            *(unsigned short*)(obase + LA_PLANE + (r0+3) * LA_STRIDE + wrow * 2) = (unsigned short)(q23 >> 16);
        }
        xv_cur = xv_nxt;
    }

    // ---- fc on h_512 (member 0 only; own cols already in LDS parity 0) ---
    if (m != 0) return;
    {
        const unsigned texp = 0;                           // tag of h_512
        const unsigned char* slab_r = ex + (0 * NG + g) * SLAB;
        uintx4 Pf[7];
        #pragma unroll
        for (int r = 0; r < 7; ++r) Pf[r] = ld_ag_b128_async(slab_r + poff[r]);
        if (tid < 7) poll_flag(flagbase + (tid + 1), (unsigned)T_STEPS + 1u);
        wait_vm0();
        __syncthreads();
        int it = 0;
        for (;;) {
            unsigned bad = 0;
            #pragma unroll
            for (int r = 0; r < 7; ++r)
                bad |= (Pf[r].x ^ texp) | (Pf[r].y ^ texp)
                     | (Pf[r].z ^ texp) | (Pf[r].w ^ texp);
            if (!(bad & 0x80000000u) || ++it >= TAG_CAP) break;
            #pragma unroll
            for (int r = 0; r < 7; ++r) Pf[r] = ld_ag_b128_async(slab_r + poff[r]);
            wait_vm0();
        }
        unsigned char* abase = smem;                       // parity 0
        #pragma unroll
        for (int r = 0; r < 7; ++r) {
            const int pm = r + 1;
            ull hi, lo;
            pack_hilo(__uint_as_float(Pf[r].x & 0x7fffffffu),
                      __uint_as_float(Pf[r].y & 0x7fffffffu),
                      __uint_as_float(Pf[r].z & 0x7fffffffu),
                      __uint_as_float(Pf[r].w & 0x7fffffffu), hi, lo);
            const int base = prow * LA_STRIDE + pm * 128 + pc4 * 8;
            *(ull*)(abase + base)            = hi;
            *(ull*)(abase + LA_PLANE + base) = lo;
        }
    }
    __syncthreads();
    for (int idx = tid; idx < 384; idx += 256) {
        const int row = idx / 24, o = idx % 24;
        const float* wp = fc_w + o * 512;
        float s = 0.f;
        for (int k = 0; k < 512; k += 4) {
            bfx4 hv = *(const bfx4*)(smem + row * LA_STRIDE + k * 2);
            bfx4 lv = *(const bfx4*)(smem + LA_PLANE + row * LA_STRIDE + k * 2);
            const float4 wv = *(const float4*)(wp + k);
            s += (bf2f(hv[0]) + bf2f(lv[0])) * wv.x;
            s += (bf2f(hv[1]) + bf2f(lv[1])) * wv.y;
            s += (bf2f(hv[2]) + bf2f(lv[2])) * wv.z;
            s += (bf2f(hv[3]) + bf2f(lv[3])) * wv.w;
        }
        out[(g * 16 + row) * 24 + o] = s + fc_b[o];
    }
}

extern "C" void kernel_launch(void* const* d_in, const int* in_sizes, int n_in,
                              void* d_out, int out_size, void* d_ws, size_t ws_size,
                              hipStream_t stream) {
    (void)in_sizes; (void)n_in; (void)out_size; (void)ws_size;
    const float* x    = (const float*)d_in[0];
    const float* W_ih = (const float*)d_in[1];
    const float* W_hh = (const float*)d_in[2];
    const float* b_ih = (const float*)d_in[3];
    const float* b_hh = (const float*)d_in[4];
    const float* fc_w = (const float*)d_in[5];
    const float* fc_b = (const float*)d_in[6];
    rnn_persistent<<<NG * NM, 256, 0, stream>>>(x, W_ih, W_hh, b_ih, b_hh,
                                                fc_w, fc_b, (float*)d_out,
                                                (unsigned char*)d_ws);
}

// Round 13
// 1473.936 us; speedup vs baseline: 1.3152x; 1.0382x over previous
//
#include <hip/hip_runtime.h>

// ---------------------------------------------------------------------------
// ReLU-RNN (B=256, T=512, I=64, H=512, O=24), fp32 in/out.  Round 19.
//
// 16 groups (16 batch rows) x 8 members (64 hid cols) = 128 blocks x 256 thr.
//   [round-19] EXACT round-14 structure restored (verified 1403us steady):
//              3-acc MFMA single 18-iter loop (round-18's 2x8 split cost
//              ~70us via worse LDS/MFMA scheduling), flag store back at
//              epilogue END.  Kept ONLY the t=0 forced reload (+sched
//              barrier, rule #18) -- closes the cross-dispatch tag0 race
//              (prev-dispatch h_512 in parity-0 slab carries tag0 == t=0
//              texp) for ~0.3us one-time cost.
//   [round-14] sc1 scope.  [round-12] absolute flag sequence, no nonce.
//   [round-11] x prefetch one step ahead; epilogue global-stores-first.
//   [round-10] v_cvt_pk_bf16_f32 packing.
// Exchange = tagged fp32 (sign bit = slab-parity tag; h>=0 after relu):
//   * flags (agent-scope, 7 polling threads) throttle the wait
//   * sign-bit tags carry data-freshness correctness
//   * phase-1 SPECULATIVE partner loads issued before the poll
//   * phase-2 bounded per-thread tag-retry fixes stale spans
//   * producer: tagged dword stores + flag store with NO vmcnt drain.
// LDS A-planes double-buffered by parity -> 2 barriers/step.
// W_ext=[W_hh|W_ih] (K=576) in VGPRs as bf16 hi/lo frags; bf16x3 MFMA.
// ---------------------------------------------------------------------------

#define T_STEPS 512
#define NG      16
#define NM      8
#define SLAB    32768                    // 16 rows x 512 cols fp32
#define FLAGS_OFF (2 * NG * SLAB)        // 1 MiB
#define POLL_CAP 100000
#define TAG_CAP  20000

// LDS: A planes double-buffered by parity; rows 16 x 1040B (512 bf16 + 8 pad)
#define LA_STRIDE 1040
#define LA_PLANE  16640                  // 16*1040
#define LA_PAR    33280                  // 2*LA_PLANE (hi+lo)
#define LX_OFF    66560                  // 2*LA_PAR
#define LX_STRIDE 144
#define LX_PLANE  2304                   // 16*144; total 71168 B

typedef short          short8  __attribute__((ext_vector_type(8)));
typedef unsigned short bfx4    __attribute__((ext_vector_type(4)));
typedef unsigned       uintx4  __attribute__((ext_vector_type(4)));
typedef float          floatx4 __attribute__((ext_vector_type(4)));
typedef unsigned long long ull;

__device__ __forceinline__ unsigned short f2bf(float x) {
    unsigned u = __float_as_uint(x);
    u = (u + 0x7fffu + ((u >> 16) & 1u)) >> 16;   // RNE
    return (unsigned short)u;
}
__device__ __forceinline__ float bf2f(unsigned short h) {
    return __uint_as_float(((unsigned)h) << 16);
}
// HW packed f32->bf16 (RNE); dst.lo16=cvt(a), dst.hi16=cvt(b)
__device__ __forceinline__ unsigned cvtpk(float a, float b) {
    unsigned r;
    asm("v_cvt_pk_bf16_f32 %0, %1, %2" : "=v"(r) : "v"(a), "v"(b));
    return r;
}
// 4 fp32 -> packed bf16 hi plane (4x16b) + lo plane (residual, 4x16b)
__device__ __forceinline__ void pack_hilo(float f0, float f1, float f2, float f3,
                                          ull& hi, ull& lo) {
    const unsigned h01 = cvtpk(f0, f1), h23 = cvtpk(f2, f3);
    const float l0 = f0 - __uint_as_float(h01 << 16);
    const float l1 = f1 - __uint_as_float(h01 & 0xffff0000u);
    const float l2 = f2 - __uint_as_float(h23 << 16);
    const float l3 = f3 - __uint_as_float(h23 & 0xffff0000u);
    const unsigned q01 = cvtpk(l0, l1), q23 = cvtpk(l2, l3);
    hi = (ull)h01 | ((ull)h23 << 32);
    lo = (ull)q01 | ((ull)q23 << 32);
}
__device__ __forceinline__ void st_ag_u32(void* p, unsigned v) {
    __hip_atomic_store((unsigned*)p, v, __ATOMIC_RELAXED, __HIP_MEMORY_SCOPE_AGENT);
}
__device__ __forceinline__ unsigned ld_ag_u32(const void* p) {
    return __hip_atomic_load((const unsigned*)p, __ATOMIC_RELAXED, __HIP_MEMORY_SCOPE_AGENT);
}
// AGENT-scope (sc1) data ops
__device__ __forceinline__ uintx4 ld_ag_b128_async(const void* p) {
    uintx4 v;
    asm volatile("global_load_dwordx4 %0, %1, off sc1"
                 : "=v"(v) : "v"(p) : "memory");
    return v;
}
__device__ __forceinline__ void st_ag_b32(void* p, unsigned v) {
    asm volatile("global_store_dword %0, %1, off sc1"
                 :: "v"(p), "v"(v) : "memory");
}
__device__ __forceinline__ void st_ag_b128(void* p, uintx4 v) {
    asm volatile("global_store_dwordx4 %0, %1, off sc1"
                 :: "v"(p), "v"(v) : "memory");
}
__device__ __forceinline__ void wait_vm0() {
    asm volatile("s_waitcnt vmcnt(0)" ::: "memory");
}
__device__ __forceinline__ void poll_flag(const unsigned* p, unsigned want) {
    int it = 0;
    for (;;) {
        unsigned f = ld_ag_u32(p);
        if (f == want || f == want + 1u) return;
        if (++it >= POLL_CAP) return;            // tags still protect data
    }
}

__global__ __launch_bounds__(256, 1) void rnn_persistent(
    const float* __restrict__ x,     const float* __restrict__ W_ih,
    const float* __restrict__ W_hh,  const float* __restrict__ b_ih,
    const float* __restrict__ b_hh,  const float* __restrict__ fc_w,
    const float* __restrict__ fc_b,  float* __restrict__ out,
    unsigned char* __restrict__ ws)
{
    const int tid  = threadIdx.x;
    const int lane = tid & 63;
    const int w    = tid >> 6;        // wave 0..3
    const int n    = lane & 15;
    const int quad = lane >> 4;

    const int bid = blockIdx.x;
    const int g = bid >> 3;           // group 0..15
    const int m = bid & 7;            // member 0..7

    unsigned char* ex = (unsigned char*)ws;
    unsigned* flagbase = (unsigned*)(ex + FLAGS_OFF + g * 64);
    __shared__ __align__(16) unsigned char smem[LX_OFF + 2 * LX_PLANE];

    // ---- W fragments: wave w holds cols (=W rows) m*64+w*16 .. +16 ----
    const int wrow = m * 64 + w * 16 + n;
    short8 Whi[18], Wlo[18];
    #pragma unroll
    for (int kt = 0; kt < 18; ++kt) {
        const float* p = (kt < 16) ? (W_hh + wrow * 512 + kt * 32 + quad * 8)
                                   : (W_ih + wrow * 64 + (kt - 16) * 32 + quad * 8);
        #pragma unroll
        for (int jj = 0; jj < 8; ++jj) {
            float f = p[jj];
            unsigned short h = f2bf(f);
            Whi[kt][jj] = (short)h;
            Wlo[kt][jj] = (short)f2bf(f - bf2f(h));
        }
    }
    const float bias_i = b_ih[wrow] + b_hh[wrow];

    // ---- per-thread partner span mapping (row prow, 16B at pc4) ----
    const int prow = tid >> 4, pc4 = tid & 15;
    int poff[7];
    #pragma unroll
    for (int r = 0; r < 7; ++r) {
        const int pm = r + (r >= m ? 1 : 0);
        poff[r] = prow * 2048 + pm * 256 + pc4 * 16;
    }

    // ---- init: own chunk = +0.0 (tag0) in parity-0 slab; own LDS cols = 0
    {
        uintx4 z = {0u, 0u, 0u, 0u};
        st_ag_b128(ex + g * SLAB + prow * 2048 + m * 256 + pc4 * 16, z);
        #pragma unroll
        for (int r = 0; r < 4; ++r) {
            const int row = quad * 4 + r;
            *(unsigned short*)(smem + 0 * LA_PLANE + row * LA_STRIDE + wrow * 2) = 0;
            *(unsigned short*)(smem + LA_PLANE + row * LA_STRIDE + wrow * 2) = 0;
        }
    }
    wait_vm0();
    __syncthreads();
    // init flag = 1 ("h_0 ready"); zeros drained before this store.
    if (tid == 0) st_ag_u32(flagbase + m, 1u);

    // ---- recurrence ------------------------------------------------------
    const int xrow = tid >> 4, xi4 = tid & 15;
    const float* xbase = x + (size_t)(g * 16 + xrow) * T_STEPS * 64 + xi4 * 4;
    // x prefetch: xv_cur holds x_t; load for t=0 up front (prologue only).
    float4 xv_cur = *(const float4*)(xbase + 0 * 64);
    for (int t = 0; t < T_STEPS; ++t) {
        const unsigned texp = (((unsigned)t >> 1) & 1u) << 31;
        const unsigned char* slab_r = ex + ((t & 1) * NG + g) * SLAB;

        // phase-1: speculative partner loads (issued at step top ->
        // serviced DURING the flag park; round-17 lesson: not earlier)
        uintx4 P[7];
        #pragma unroll
        for (int r = 0; r < 7; ++r) P[r] = ld_ag_b128_async(slab_r + poff[r]);

        // flag park (7 threads only - no data-poll storm); want = t+1
        if (tid < 7) {
            const int pm = tid + (tid >= m ? 1 : 0);
            poll_flag(flagbase + pm, (unsigned)t + 1u);
        }
        wait_vm0();
        __syncthreads();                                   // (a)

        // t=0: forced reload (closes cross-dispatch tag0 collision race;
        // flag=1 implies partner zeros drained -> reload is guaranteed fresh)
        if (t == 0) {
            #pragma unroll
            for (int r = 0; r < 7; ++r) P[r] = ld_ag_b128_async(slab_r + poff[r]);
            wait_vm0();
            __builtin_amdgcn_sched_barrier(0);
        }

        // phase-2: bounded per-thread tag-retry for stale spans
        {
            int it = 0;
            for (;;) {
                unsigned bad = 0;
                #pragma unroll
                for (int r = 0; r < 7; ++r)
                    bad |= (P[r].x ^ texp) | (P[r].y ^ texp)
                         | (P[r].z ^ texp) | (P[r].w ^ texp);
                if (!(bad & 0x80000000u) || ++it >= TAG_CAP) break;
                #pragma unroll
                for (int r = 0; r < 7; ++r) P[r] = ld_ag_b128_async(slab_r + poff[r]);
                wait_vm0();
            }
        }

        // x prefetch for t+1 (HBM; issued AFTER retry so no drain waits on it;
        // consumed next step => full-step latency hiding)
        const int tn = (t + 1 < T_STEPS) ? (t + 1) : (T_STEPS - 1);
        const float4 xv_nxt = *(const float4*)(xbase + (size_t)tn * 64);

        // convert partner cols -> LDS A planes (parity t&1)
        unsigned char* abase = smem + (t & 1) * LA_PAR;
        #pragma unroll
        for (int r = 0; r < 7; ++r) {
            const int pm = r + (r >= m ? 1 : 0);
            ull hi, lo;
            pack_hilo(__uint_as_float(P[r].x & 0x7fffffffu),
                      __uint_as_float(P[r].y & 0x7fffffffu),
                      __uint_as_float(P[r].z & 0x7fffffffu),
                      __uint_as_float(P[r].w & 0x7fffffffu), hi, lo);
            const int base = prow * LA_STRIDE + pm * 128 + pc4 * 8;
            *(ull*)(abase + base)            = hi;
            *(ull*)(abase + LA_PLANE + base) = lo;
        }
        // stage x_t (fp32 -> bf16 hi/lo) from prefetched regs
        {
            ull hi, lo;
            pack_hilo(xv_cur.x, xv_cur.y, xv_cur.z, xv_cur.w, hi, lo);
            *(ull*)(smem + LX_OFF + xrow * LX_STRIDE + xi4 * 8)            = hi;
            *(ull*)(smem + LX_OFF + LX_PLANE + xrow * LX_STRIDE + xi4 * 8) = lo;
        }
        __syncthreads();                                   // (b)

        // MFMA: C[16 batch x 16 cols] over K=576, bf16x3
        floatx4 c0 = {0.f,0.f,0.f,0.f}, c1 = {0.f,0.f,0.f,0.f}, c2 = {0.f,0.f,0.f,0.f};
        #pragma unroll
        for (int kt = 0; kt < 16; ++kt) {
            const unsigned char* ba = abase + n * LA_STRIDE + kt * 64 + quad * 16;
            short8 ah = *(const short8*)(ba);
            short8 al = *(const short8*)(ba + LA_PLANE);
            c0 = __builtin_amdgcn_mfma_f32_16x16x32_bf16(ah, Whi[kt], c0, 0, 0, 0);
            c1 = __builtin_amdgcn_mfma_f32_16x16x32_bf16(al, Whi[kt], c1, 0, 0, 0);
            c2 = __builtin_amdgcn_mfma_f32_16x16x32_bf16(ah, Wlo[kt], c2, 0, 0, 0);
        }
        #pragma unroll
        for (int kt = 16; kt < 18; ++kt) {
            const unsigned char* ba = smem + LX_OFF + n * LX_STRIDE + (kt - 16) * 64 + quad * 16;
            short8 ah = *(const short8*)(ba);
            short8 al = *(const short8*)(ba + LX_PLANE);
            c0 = __builtin_amdgcn_mfma_f32_16x16x32_bf16(ah, Whi[kt], c0, 0, 0, 0);
            c1 = __builtin_amdgcn_mfma_f32_16x16x32_bf16(al, Whi[kt], c1, 0, 0, 0);
            c2 = __builtin_amdgcn_mfma_f32_16x16x32_bf16(ah, Wlo[kt], c2, 0, 0, 0);
        }

        // epilogue: tagged GLOBAL stores first (producer visibility ASAP),
        // then LDS own-col writes, then flag.  NO drain: tags carry freshness.
        const unsigned otag = ((((unsigned)t + 1u) >> 1) & 1u) << 31;
        unsigned char* slab_w = ex + (((t + 1) & 1) * NG + g) * SLAB;
        unsigned char* obase  = smem + ((t + 1) & 1) * LA_PAR;
        const floatx4 cs = c0 + c1 + c2;
        const int r0 = quad * 4;
        {
            const float v0 = fmaxf(cs[0] + bias_i, 0.f);
            const float v1 = fmaxf(cs[1] + bias_i, 0.f);
            const float v2 = fmaxf(cs[2] + bias_i, 0.f);
            const float v3 = fmaxf(cs[3] + bias_i, 0.f);
            st_ag_b32(slab_w + (r0+0) * 2048 + wrow * 4, __float_as_uint(v0) | otag);
            st_ag_b32(slab_w + (r0+1) * 2048 + wrow * 4, __float_as_uint(v1) | otag);
            st_ag_b32(slab_w + (r0+2) * 2048 + wrow * 4, __float_as_uint(v2) | otag);
            st_ag_b32(slab_w + (r0+3) * 2048 + wrow * 4, __float_as_uint(v3) | otag);
            const unsigned h01 = cvtpk(v0, v1), h23 = cvtpk(v2, v3);
            const float l0 = v0 - __uint_as_float(h01 << 16);
            const float l1 = v1 - __uint_as_float(h01 & 0xffff0000u);
            const float l2 = v2 - __uint_as_float(h23 << 16);
            const float l3 = v3 - __uint_as_float(h23 & 0xffff0000u);
            const unsigned q01 = cvtpk(l0, l1), q23 = cvtpk(l2, l3);
            *(unsigned short*)(obase + (r0+0) * LA_STRIDE + wrow * 2) = (unsigned short)(h01 & 0xffffu);
            *(unsigned short*)(obase + (r0+1) * LA_STRIDE + wrow * 2) = (unsigned short)(h01 >> 16);
            *(unsigned short*)(obase + (r0+2) * LA_STRIDE + wrow * 2) = (unsigned short)(h23 & 0xffffu);
            *(unsigned short*)(obase + (r0+3) * LA_STRIDE + wrow * 2) = (unsigned short)(h23 >> 16);
            *(unsigned short*)(obase + LA_PLANE + (r0+0) * LA_STRIDE + wrow * 2) = (unsigned short)(q01 & 0xffffu);
            *(unsigned short*)(obase + LA_PLANE + (r0+1) * LA_STRIDE + wrow * 2) = (unsigned short)(q01 >> 16);
            *(unsigned short*)(obase + LA_PLANE + (r0+2) * LA_STRIDE + wrow * 2) = (unsigned short)(q23 & 0xffffu);
            *(unsigned short*)(obase + LA_PLANE + (r0+3) * LA_STRIDE + wrow * 2) = (unsigned short)(q23 >> 16);
        }
        if (tid == 0) st_ag_u32(flagbase + m, (unsigned)t + 2u);
        xv_cur = xv_nxt;
    }

    // ---- fc on h_512 (member 0 only; own cols already in LDS parity 0) ---
    if (m != 0) return;
    {
        const unsigned texp = 0;                           // tag of h_512
        const unsigned char* slab_r = ex + (0 * NG + g) * SLAB;
        uintx4 P[7];
        #pragma unroll
        for (int r = 0; r < 7; ++r) P[r] = ld_ag_b128_async(slab_r + poff[r]);
        if (tid < 7) poll_flag(flagbase + (tid + 1), (unsigned)T_STEPS + 1u);
        wait_vm0();
        __syncthreads();
        int it = 0;
        for (;;) {
            unsigned bad = 0;
            #pragma unroll
            for (int r = 0; r < 7; ++r)
                bad |= (P[r].x ^ texp) | (P[r].y ^ texp)
                     | (P[r].z ^ texp) | (P[r].w ^ texp);
            if (!(bad & 0x80000000u) || ++it >= TAG_CAP) break;
            #pragma unroll
            for (int r = 0; r < 7; ++r) P[r] = ld_ag_b128_async(slab_r + poff[r]);
            wait_vm0();
        }
        unsigned char* abase = smem;                       // parity 0
        #pragma unroll
        for (int r = 0; r < 7; ++r) {
            const int pm = r + 1;
            ull hi, lo;
            pack_hilo(__uint_as_float(P[r].x & 0x7fffffffu),
                      __uint_as_float(P[r].y & 0x7fffffffu),
                      __uint_as_float(P[r].z & 0x7fffffffu),
                      __uint_as_float(P[r].w & 0x7fffffffu), hi, lo);
            const int base = prow * LA_STRIDE + pm * 128 + pc4 * 8;
            *(ull*)(abase + base)            = hi;
            *(ull*)(abase + LA_PLANE + base) = lo;
        }
    }
    __syncthreads();
    for (int idx = tid; idx < 384; idx += 256) {
        const int row = idx / 24, o = idx % 24;
        const float* wp = fc_w + o * 512;
        float s = 0.f;
        for (int k = 0; k < 512; k += 4) {
            bfx4 hv = *(const bfx4*)(smem + row * LA_STRIDE + k * 2);
            bfx4 lv = *(const bfx4*)(smem + LA_PLANE + row * LA_STRIDE + k * 2);
            const float4 wv = *(const float4*)(wp + k);
            s += (bf2f(hv[0]) + bf2f(lv[0])) * wv.x;
            s += (bf2f(hv[1]) + bf2f(lv[1])) * wv.y;
            s += (bf2f(hv[2]) + bf2f(lv[2])) * wv.z;
            s += (bf2f(hv[3]) + bf2f(lv[3])) * wv.w;
        }
        out[(g * 16 + row) * 24 + o] = s + fc_b[o];
    }
}

extern "C" void kernel_launch(void* const* d_in, const int* in_sizes, int n_in,
                              void* d_out, int out_size, void* d_ws, size_t ws_size,
                              hipStream_t stream) {
    (void)in_sizes; (void)n_in; (void)out_size; (void)ws_size;
    const float* x    = (const float*)d_in[0];
    const float* W_ih = (const float*)d_in[1];
    const float* W_hh = (const float*)d_in[2];
    const float* b_ih = (const float*)d_in[3];
    const float* b_hh = (const float*)d_in[4];
    const float* fc_w = (const float*)d_in[5];
    const float* fc_b = (const float*)d_in[6];
    rnn_persistent<<<NG * NM, 256, 0, stream>>>(x, W_ih, W_hh, b_ih, b_hh,
                                                fc_w, fc_b, (float*)d_out,
                                                (unsigned char*)d_ws);
}

// Round 14
// 1437.393 us; speedup vs baseline: 1.3486x; 1.0254x over previous
//
#include <hip/hip_runtime.h>

// ---------------------------------------------------------------------------
// ReLU-RNN (B=256, T=512, I=64, H=512, O=24), fp32 in/out.  Round 20.
//
// 16 groups (16 batch rows) x 8 members (64 hid cols) = 128 blocks x 256 thr.
//   [round-20] PACKED-BF16 EXCHANGE: producer transmits (hi16<<16)|lo16 per
//              element (it already computes hi/lo for its own LDS writes).
//              Bit31 = hi's sign = genuinely 0 (h>=0) -> reused as parity
//              tag, SAME bit/check/retry as the fp32 scheme.  Consumer
//              convert: pack_hilo (4 cvtpk + 4 subs, ~16 VALU) -> pure
//              byte-select unpack (~6-10 VALU, v_perm-able).  Identical
//              bf16 values transmitted => bit-identical output.  Precedent:
//              round-5's convert-cut translated 1:1 into time.
//   [round-19] round-14 structure + t=0 forced reload (cross-dispatch tag0
//              race closed).  [round-14] sc1 scope.  [round-12] absolute
//              flag sequence.  [round-11] x prefetch; stores-first epilogue.
//   [round-10] v_cvt_pk_bf16_f32 packing (x staging).
// Exchange = tagged packed bf16 (bit31 = slab-parity tag):
//   * flags (agent-scope, 7 polling threads) throttle the wait
//   * bit31 tags carry data-freshness correctness
//   * phase-1 SPECULATIVE partner loads issued at step top (serviced
//     DURING the park -- round-17 lesson: not earlier)
//   * phase-2 bounded per-thread tag-retry fixes stale spans
//   * producer: tagged dword stores + flag store with NO vmcnt drain.
// LDS A-planes double-buffered by parity -> 2 barriers/step.
// W_ext=[W_hh|W_ih] (K=576) in VGPRs as bf16 hi/lo frags; bf16x3 MFMA.
// ---------------------------------------------------------------------------

#define T_STEPS 512
#define NG      16
#define NM      8
#define SLAB    32768                    // 16 rows x 512 cols (4B words)
#define FLAGS_OFF (2 * NG * SLAB)        // 1 MiB
#define POLL_CAP 100000
#define TAG_CAP  20000

// LDS: A planes double-buffered by parity; rows 16 x 1040B (512 bf16 + 8 pad)
#define LA_STRIDE 1040
#define LA_PLANE  16640                  // 16*1040
#define LA_PAR    33280                  // 2*LA_PLANE (hi+lo)
#define LX_OFF    66560                  // 2*LA_PAR
#define LX_STRIDE 144
#define LX_PLANE  2304                   // 16*144; total 71168 B

typedef short          short8  __attribute__((ext_vector_type(8)));
typedef unsigned short bfx4    __attribute__((ext_vector_type(4)));
typedef unsigned       uintx4  __attribute__((ext_vector_type(4)));
typedef float          floatx4 __attribute__((ext_vector_type(4)));
typedef unsigned long long ull;

__device__ __forceinline__ unsigned short f2bf(float x) {
    unsigned u = __float_as_uint(x);
    u = (u + 0x7fffu + ((u >> 16) & 1u)) >> 16;   // RNE
    return (unsigned short)u;
}
__device__ __forceinline__ float bf2f(unsigned short h) {
    return __uint_as_float(((unsigned)h) << 16);
}
// HW packed f32->bf16 (RNE); dst.lo16=cvt(a), dst.hi16=cvt(b)
__device__ __forceinline__ unsigned cvtpk(float a, float b) {
    unsigned r;
    asm("v_cvt_pk_bf16_f32 %0, %1, %2" : "=v"(r) : "v"(a), "v"(b));
    return r;
}
// 4 fp32 -> packed bf16 hi plane (4x16b) + lo plane (residual, 4x16b)
__device__ __forceinline__ void pack_hilo(float f0, float f1, float f2, float f3,
                                          ull& hi, ull& lo) {
    const unsigned h01 = cvtpk(f0, f1), h23 = cvtpk(f2, f3);
    const float l0 = f0 - __uint_as_float(h01 << 16);
    const float l1 = f1 - __uint_as_float(h01 & 0xffff0000u);
    const float l2 = f2 - __uint_as_float(h23 << 16);
    const float l3 = f3 - __uint_as_float(h23 & 0xffff0000u);
    const unsigned q01 = cvtpk(l0, l1), q23 = cvtpk(l2, l3);
    hi = (ull)h01 | ((ull)h23 << 32);
    lo = (ull)q01 | ((ull)q23 << 32);
}
// packed-word exchange unpack: w = (hi16<<16)|lo16, bit31 = tag (hi sign = 0)
__device__ __forceinline__ void unpack_hilo(uintx4 Pw, ull& hi, ull& lo) {
    hi = (ull)((Pw.x >> 16) & 0x7fffu)
       | ((ull)((Pw.y >> 16) & 0x7fffu) << 16)
       | ((ull)((Pw.z >> 16) & 0x7fffu) << 32)
       | ((ull)((Pw.w >> 16) & 0x7fffu) << 48);
    lo = (ull)(Pw.x & 0xffffu)
       | ((ull)(Pw.y & 0xffffu) << 16)
       | ((ull)(Pw.z & 0xffffu) << 32)
       | ((ull)(Pw.w & 0xffffu) << 48);
}
__device__ __forceinline__ void st_ag_u32(void* p, unsigned v) {
    __hip_atomic_store((unsigned*)p, v, __ATOMIC_RELAXED, __HIP_MEMORY_SCOPE_AGENT);
}
__device__ __forceinline__ unsigned ld_ag_u32(const void* p) {
    return __hip_atomic_load((const unsigned*)p, __ATOMIC_RELAXED, __HIP_MEMORY_SCOPE_AGENT);
}
// AGENT-scope (sc1) data ops
__device__ __forceinline__ uintx4 ld_ag_b128_async(const void* p) {
    uintx4 v;
    asm volatile("global_load_dwordx4 %0, %1, off sc1"
                 : "=v"(v) : "v"(p) : "memory");
    return v;
}
__device__ __forceinline__ void st_ag_b32(void* p, unsigned v) {
    asm volatile("global_store_dword %0, %1, off sc1"
                 :: "v"(p), "v"(v) : "memory");
}
__device__ __forceinline__ void st_ag_b128(void* p, uintx4 v) {
    asm volatile("global_store_dwordx4 %0, %1, off sc1"
                 :: "v"(p), "v"(v) : "memory");
}
__device__ __forceinline__ void wait_vm0() {
    asm volatile("s_waitcnt vmcnt(0)" ::: "memory");
}
__device__ __forceinline__ void poll_flag(const unsigned* p, unsigned want) {
    int it = 0;
    for (;;) {
        unsigned f = ld_ag_u32(p);
        if (f == want || f == want + 1u) return;
        if (++it >= POLL_CAP) return;            // tags still protect data
    }
}

__global__ __launch_bounds__(256, 1) void rnn_persistent(
    const float* __restrict__ x,     const float* __restrict__ W_ih,
    const float* __restrict__ W_hh,  const float* __restrict__ b_ih,
    const float* __restrict__ b_hh,  const float* __restrict__ fc_w,
    const float* __restrict__ fc_b,  float* __restrict__ out,
    unsigned char* __restrict__ ws)
{
    const int tid  = threadIdx.x;
    const int lane = tid & 63;
    const int w    = tid >> 6;        // wave 0..3
    const int n    = lane & 15;
    const int quad = lane >> 4;

    const int bid = blockIdx.x;
    const int g = bid >> 3;           // group 0..15
    const int m = bid & 7;            // member 0..7

    unsigned char* ex = (unsigned char*)ws;
    unsigned* flagbase = (unsigned*)(ex + FLAGS_OFF + g * 64);
    __shared__ __align__(16) unsigned char smem[LX_OFF + 2 * LX_PLANE];

    // ---- W fragments: wave w holds cols (=W rows) m*64+w*16 .. +16 ----
    const int wrow = m * 64 + w * 16 + n;
    short8 Whi[18], Wlo[18];
    #pragma unroll
    for (int kt = 0; kt < 18; ++kt) {
        const float* p = (kt < 16) ? (W_hh + wrow * 512 + kt * 32 + quad * 8)
                                   : (W_ih + wrow * 64 + (kt - 16) * 32 + quad * 8);
        #pragma unroll
        for (int jj = 0; jj < 8; ++jj) {
            float f = p[jj];
            unsigned short h = f2bf(f);
            Whi[kt][jj] = (short)h;
            Wlo[kt][jj] = (short)f2bf(f - bf2f(h));
        }
    }
    const float bias_i = b_ih[wrow] + b_hh[wrow];

    // ---- per-thread partner span mapping (row prow, 16B at pc4) ----
    const int prow = tid >> 4, pc4 = tid & 15;
    int poff[7];
    #pragma unroll
    for (int r = 0; r < 7; ++r) {
        const int pm = r + (r >= m ? 1 : 0);
        poff[r] = prow * 2048 + pm * 256 + pc4 * 16;
    }

    // ---- init: own chunk = 0 (tag0; hi=lo=0 -> h=0) in parity-0 slab ----
    {
        uintx4 z = {0u, 0u, 0u, 0u};
        st_ag_b128(ex + g * SLAB + prow * 2048 + m * 256 + pc4 * 16, z);
        #pragma unroll
        for (int r = 0; r < 4; ++r) {
            const int row = quad * 4 + r;
            *(unsigned short*)(smem + 0 * LA_PLANE + row * LA_STRIDE + wrow * 2) = 0;
            *(unsigned short*)(smem + LA_PLANE + row * LA_STRIDE + wrow * 2) = 0;
        }
    }
    wait_vm0();
    __syncthreads();
    // init flag = 1 ("h_0 ready"); zeros drained before this store.
    if (tid == 0) st_ag_u32(flagbase + m, 1u);

    // ---- recurrence ------------------------------------------------------
    const int xrow = tid >> 4, xi4 = tid & 15;
    const float* xbase = x + (size_t)(g * 16 + xrow) * T_STEPS * 64 + xi4 * 4;
    // x prefetch: xv_cur holds x_t; load for t=0 up front (prologue only).
    float4 xv_cur = *(const float4*)(xbase + 0 * 64);
    for (int t = 0; t < T_STEPS; ++t) {
        const unsigned texp = (((unsigned)t >> 1) & 1u) << 31;
        const unsigned char* slab_r = ex + ((t & 1) * NG + g) * SLAB;

        // phase-1: speculative partner loads (issued at step top ->
        // serviced DURING the flag park; round-17 lesson: not earlier)
        uintx4 P[7];
        #pragma unroll
        for (int r = 0; r < 7; ++r) P[r] = ld_ag_b128_async(slab_r + poff[r]);

        // flag park (7 threads only - no data-poll storm); want = t+1
        if (tid < 7) {
            const int pm = tid + (tid >= m ? 1 : 0);
            poll_flag(flagbase + pm, (unsigned)t + 1u);
        }
        wait_vm0();
        __syncthreads();                                   // (a)

        // t=0: forced reload (closes cross-dispatch tag0 collision race;
        // flag=1 implies partner zeros drained -> reload is guaranteed fresh)
        if (t == 0) {
            #pragma unroll
            for (int r = 0; r < 7; ++r) P[r] = ld_ag_b128_async(slab_r + poff[r]);
            wait_vm0();
            __builtin_amdgcn_sched_barrier(0);
        }

        // phase-2: bounded per-thread tag-retry for stale spans
        {
            int it = 0;
            for (;;) {
                unsigned bad = 0;
                #pragma unroll
                for (int r = 0; r < 7; ++r)
                    bad |= (P[r].x ^ texp) | (P[r].y ^ texp)
                         | (P[r].z ^ texp) | (P[r].w ^ texp);
                if (!(bad & 0x80000000u) || ++it >= TAG_CAP) break;
                #pragma unroll
                for (int r = 0; r < 7; ++r) P[r] = ld_ag_b128_async(slab_r + poff[r]);
                wait_vm0();
            }
        }

        // x prefetch for t+1 (HBM; issued AFTER retry so no drain waits on it;
        // consumed next step => full-step latency hiding)
        const int tn = (t + 1 < T_STEPS) ? (t + 1) : (T_STEPS - 1);
        const float4 xv_nxt = *(const float4*)(xbase + (size_t)tn * 64);

        // unpack partner cols (packed bf16 words) -> LDS A planes (parity t&1)
        unsigned char* abase = smem + (t & 1) * LA_PAR;
        #pragma unroll
        for (int r = 0; r < 7; ++r) {
            const int pm = r + (r >= m ? 1 : 0);
            ull hi, lo;
            unpack_hilo(P[r], hi, lo);
            const int base = prow * LA_STRIDE + pm * 128 + pc4 * 8;
            *(ull*)(abase + base)            = hi;
            *(ull*)(abase + LA_PLANE + base) = lo;
        }
        // stage x_t (fp32 -> bf16 hi/lo) from prefetched regs
        {
            ull hi, lo;
            pack_hilo(xv_cur.x, xv_cur.y, xv_cur.z, xv_cur.w, hi, lo);
            *(ull*)(smem + LX_OFF + xrow * LX_STRIDE + xi4 * 8)            = hi;
            *(ull*)(smem + LX_OFF + LX_PLANE + xrow * LX_STRIDE + xi4 * 8) = lo;
        }
        __syncthreads();                                   // (b)

        // MFMA: C[16 batch x 16 cols] over K=576, bf16x3
        floatx4 c0 = {0.f,0.f,0.f,0.f}, c1 = {0.f,0.f,0.f,0.f}, c2 = {0.f,0.f,0.f,0.f};
        #pragma unroll
        for (int kt = 0; kt < 16; ++kt) {
            const unsigned char* ba = abase + n * LA_STRIDE + kt * 64 + quad * 16;
            short8 ah = *(const short8*)(ba);
            short8 al = *(const short8*)(ba + LA_PLANE);
            c0 = __builtin_amdgcn_mfma_f32_16x16x32_bf16(ah, Whi[kt], c0, 0, 0, 0);
            c1 = __builtin_amdgcn_mfma_f32_16x16x32_bf16(al, Whi[kt], c1, 0, 0, 0);
            c2 = __builtin_amdgcn_mfma_f32_16x16x32_bf16(ah, Wlo[kt], c2, 0, 0, 0);
        }
        #pragma unroll
        for (int kt = 16; kt < 18; ++kt) {
            const unsigned char* ba = smem + LX_OFF + n * LX_STRIDE + (kt - 16) * 64 + quad * 16;
            short8 ah = *(const short8*)(ba);
            short8 al = *(const short8*)(ba + LX_PLANE);
            c0 = __builtin_amdgcn_mfma_f32_16x16x32_bf16(ah, Whi[kt], c0, 0, 0, 0);
            c1 = __builtin_amdgcn_mfma_f32_16x16x32_bf16(al, Whi[kt], c1, 0, 0, 0);
            c2 = __builtin_amdgcn_mfma_f32_16x16x32_bf16(ah, Wlo[kt], c2, 0, 0, 0);
        }

        // epilogue: cvt to hi/lo planes -> packed tagged GLOBAL stores ->
        // LDS own-col writes -> flag.  NO drain: tags carry freshness.
        const unsigned otag = ((((unsigned)t + 1u) >> 1) & 1u) << 31;
        unsigned char* slab_w = ex + (((t + 1) & 1) * NG + g) * SLAB;
        unsigned char* obase  = smem + ((t + 1) & 1) * LA_PAR;
        const floatx4 cs = c0 + c1 + c2;
        const int r0 = quad * 4;
        {
            const float v0 = fmaxf(cs[0] + bias_i, 0.f);
            const float v1 = fmaxf(cs[1] + bias_i, 0.f);
            const float v2 = fmaxf(cs[2] + bias_i, 0.f);
            const float v3 = fmaxf(cs[3] + bias_i, 0.f);
            const unsigned h01 = cvtpk(v0, v1), h23 = cvtpk(v2, v3);
            const float l0 = v0 - __uint_as_float(h01 << 16);
            const float l1 = v1 - __uint_as_float(h01 & 0xffff0000u);
            const float l2 = v2 - __uint_as_float(h23 << 16);
            const float l3 = v3 - __uint_as_float(h23 & 0xffff0000u);
            const unsigned q01 = cvtpk(l0, l1), q23 = cvtpk(l2, l3);
            // packed exchange words: hi at [31:16] (sign bit genuinely 0),
            // lo at [15:0]; tag ORed into bit31.
            st_ag_b32(slab_w + (r0+0) * 2048 + wrow * 4,
                      (h01 << 16) | (q01 & 0xffffu) | otag);
            st_ag_b32(slab_w + (r0+1) * 2048 + wrow * 4,
                      (h01 & 0xffff0000u) | (q01 >> 16) | otag);
            st_ag_b32(slab_w + (r0+2) * 2048 + wrow * 4,
                      (h23 << 16) | (q23 & 0xffffu) | otag);
            st_ag_b32(slab_w + (r0+3) * 2048 + wrow * 4,
                      (h23 & 0xffff0000u) | (q23 >> 16) | otag);
            *(unsigned short*)(obase + (r0+0) * LA_STRIDE + wrow * 2) = (unsigned short)(h01 & 0xffffu);
            *(unsigned short*)(obase + (r0+1) * LA_STRIDE + wrow * 2) = (unsigned short)(h01 >> 16);
            *(unsigned short*)(obase + (r0+2) * LA_STRIDE + wrow * 2) = (unsigned short)(h23 & 0xffffu);
            *(unsigned short*)(obase + (r0+3) * LA_STRIDE + wrow * 2) = (unsigned short)(h23 >> 16);
            *(unsigned short*)(obase + LA_PLANE + (r0+0) * LA_STRIDE + wrow * 2) = (unsigned short)(q01 & 0xffffu);
            *(unsigned short*)(obase + LA_PLANE + (r0+1) * LA_STRIDE + wrow * 2) = (unsigned short)(q01 >> 16);
            *(unsigned short*)(obase + LA_PLANE + (r0+2) * LA_STRIDE + wrow * 2) = (unsigned short)(q23 & 0xffffu);
            *(unsigned short*)(obase + LA_PLANE + (r0+3) * LA_STRIDE + wrow * 2) = (unsigned short)(q23 >> 16);
        }
        if (tid == 0) st_ag_u32(flagbase + m, (unsigned)t + 2u);
        xv_cur = xv_nxt;
    }

    // ---- fc on h_512 (member 0 only; own cols already in LDS parity 0) ---
    if (m != 0) return;
    {
        const unsigned texp = 0;                           // tag of h_512
        const unsigned char* slab_r = ex + (0 * NG + g) * SLAB;
        uintx4 P[7];
        #pragma unroll
        for (int r = 0; r < 7; ++r) P[r] = ld_ag_b128_async(slab_r + poff[r]);
        if (tid < 7) poll_flag(flagbase + (tid + 1), (unsigned)T_STEPS + 1u);
        wait_vm0();
        __syncthreads();
        int it = 0;
        for (;;) {
            unsigned bad = 0;
            #pragma unroll
            for (int r = 0; r < 7; ++r)
                bad |= (P[r].x ^ texp) | (P[r].y ^ texp)
                     | (P[r].z ^ texp) | (P[r].w ^ texp);
            if (!(bad & 0x80000000u) || ++it >= TAG_CAP) break;
            #pragma unroll
            for (int r = 0; r < 7; ++r) P[r] = ld_ag_b128_async(slab_r + poff[r]);
            wait_vm0();
        }
        unsigned char* abase = smem;                       // parity 0
        #pragma unroll
        for (int r = 0; r < 7; ++r) {
            const int pm = r + 1;
            ull hi, lo;
            unpack_hilo(P[r], hi, lo);
            const int base = prow * LA_STRIDE + pm * 128 + pc4 * 8;
            *(ull*)(abase + base)            = hi;
            *(ull*)(abase + LA_PLANE + base) = lo;
        }
    }
    __syncthreads();
    for (int idx = tid; idx < 384; idx += 256) {
        const int row = idx / 24, o = idx % 24;
        const float* wp = fc_w + o * 512;
        float s = 0.f;
        for (int k = 0; k < 512; k += 4) {
            bfx4 hv = *(const bfx4*)(smem + row * LA_STRIDE + k * 2);
            bfx4 lv = *(const bfx4*)(smem + LA_PLANE + row * LA_STRIDE + k * 2);
            const float4 wv = *(const float4*)(wp + k);
            s += (bf2f(hv[0]) + bf2f(lv[0])) * wv.x;
            s += (bf2f(hv[1]) + bf2f(lv[1])) * wv.y;
            s += (bf2f(hv[2]) + bf2f(lv[2])) * wv.z;
            s += (bf2f(hv[3]) + bf2f(lv[3])) * wv.w;
        }
        out[(g * 16 + row) * 24 + o] = s + fc_b[o];
    }
}

extern "C" void kernel_launch(void* const* d_in, const int* in_sizes, int n_in,
                              void* d_out, int out_size, void* d_ws, size_t ws_size,
                              hipStream_t stream) {
    (void)in_sizes; (void)n_in; (void)out_size; (void)ws_size;
    const float* x    = (const float*)d_in[0];
    const float* W_ih = (const float*)d_in[1];
    const float* W_hh = (const float*)d_in[2];
    const float* b_ih = (const float*)d_in[3];
    const float* b_hh = (const float*)d_in[4];
    const float* fc_w = (const float*)d_in[5];
    const float* fc_b = (const float*)d_in[6];
    rnn_persistent<<<NG * NM, 256, 0, stream>>>(x, W_ih, W_hh, b_ih, b_hh,
                                                fc_w, fc_b, (float*)d_out,
                                                (unsigned char*)d_ws);
}